// Round 4
// baseline (546.049 us; speedup 1.0000x reference)
//
#include <hip/hip_runtime.h>

// WindowAttention: B=256 windows, N=256 tokens, C=384, 12 heads, d=32.
// Pipeline (2 b-halves to fit workspace):
//   K0: cast weights -> bf16
//   K2a k_qkv : x (B,C,N) f32 -> LDS transpose (barrier) -> qkv MFMA16 GEMM + bias + l2norm
//               -> q/k/v_ws all in frag layout [bh][jl][half][tok][8] (d = jl*16+half*8+e)
//   K2b k_attn: per (b,h): stage k (copy) + v (transpose, barrier-protected);
//               MFMA32 S^T -> exp -> P via shfl_xor(32) register exchange -> MFMA32 O^T
//               -> O via shfl_xor exchange -> xa[tok][c] bf16. NO unprotected LDS RAW.
//   K3  k_proj: proj GEMM (MFMA32) -> out (B,C,N) f32
// 16x16x32 layouts: A/B: row=lane&15, k=(lane>>4)*8+j ; D: col=lane&15, row=(lane>>4)*4+r
// 32x32x16 layouts: A/B: row=lane&31, k=(lane>>5)*8+j ; D: col=lane&31, row=(reg&3)+8*(reg>>2)+4*(lane>>5)
// Softmax: |logit| <= 0.178 -> no max-subtract; clip(1e-6,1) provably no-op.

#define DIM 384
#define NT 256
#define NH 12
#define SCALE 0.17677669529663687f

typedef __bf16 bf16;
typedef __bf16 bf16x4 __attribute__((ext_vector_type(4)));
typedef __bf16 bf16x8 __attribute__((ext_vector_type(8)));
typedef float f32x4 __attribute__((ext_vector_type(4)));
typedef float f32x16 __attribute__((ext_vector_type(16)));

#define MFMA16(a, b, c) __builtin_amdgcn_mfma_f32_16x16x32_bf16(a, b, c, 0, 0, 0)
#define MFMA32(a, b, c) __builtin_amdgcn_mfma_f32_32x32x16_bf16(a, b, c, 0, 0, 0)

union U2H4 { bf16x4 h; uint2 u; };
union U4H8 { bf16x8 h; uint4 u; };

// ---------------- K0: cast weights ----------------
__global__ void k_cast_w(const float* __restrict__ qkv_w, const float* __restrict__ proj_w,
                         bf16* __restrict__ wq, bf16* __restrict__ wp) {
    int i = blockIdx.x * 256 + threadIdx.x;
    if (i < 3 * DIM * DIM) wq[i] = (bf16)qkv_w[i];
    if (i < DIM * DIM)     wp[i] = (bf16)proj_w[i];
}

// ---------------- K2a: fused transpose + qkv GEMM + bias + l2norm ----------------
__launch_bounds__(256, 3)
__global__ void k_qkv(const float* __restrict__ x, const bf16* __restrict__ wq,
                      const float* __restrict__ qkv_b,
                      bf16* __restrict__ q_ws, bf16* __restrict__ k_ws, bf16* __restrict__ v_ws,
                      int b0) {
    __shared__ bf16 xf[48][64][8];    // [c/8][tok][c&7]  49,152 B (only LDS; barrier-protected)
    const int tile = blockIdx.x;            // 0..3 (64-token tile within b)
    const int bl = blockIdx.y;              // local b (within half)
    const int b = b0 + bl;
    const int t0 = tile * 64;
    const int tid = threadIdx.x, lane = tid & 63, w = tid >> 6;
    const int l15 = lane & 15, quad = lane >> 4;

    // stage x tile -> xf (transpose + cast). 256B rows of x.
    {
        const float* xp = x + (size_t)b * DIM * NT + t0;
        int r = tid >> 4;              // c row within group of 16
        int tk = (tid & 15) * 4;       // token offset
#pragma unroll 4
        for (int it = 0; it < 24; ++it) {
            int c = it * 16 + r;
            f32x4 vv = *(const f32x4*)(xp + (size_t)c * NT + tk);
#pragma unroll
            for (int j = 0; j < 4; ++j)
                xf[c >> 3][tk + j][c & 7] = (bf16)vv[j];
        }
    }
    __syncthreads();

    // wave w handles output columns [w*288, w*288+288) in 3 chunks of 96
#pragma unroll 1
    for (int c = 0; c < 3; ++c) {
        const int cb = w * 288 + c * 96;
        f32x4 acc[6][4];
#pragma unroll
        for (int jt = 0; jt < 6; ++jt)
#pragma unroll
            for (int tt = 0; tt < 4; ++tt) acc[jt][tt] = (f32x4){0.f, 0.f, 0.f, 0.f};

        const bf16* wr[6];
#pragma unroll
        for (int jt = 0; jt < 6; ++jt)
            wr[jt] = wq + (size_t)(cb + jt * 16 + l15) * DIM + quad * 8;

#pragma unroll 2
        for (int kc = 0; kc < 12; ++kc) {
            bf16x8 afr[6], bfr[4];
#pragma unroll
            for (int jt = 0; jt < 6; ++jt) afr[jt] = *(const bf16x8*)(wr[jt] + kc * 32);
#pragma unroll
            for (int tt = 0; tt < 4; ++tt) bfr[tt] = *(const bf16x8*)&xf[kc * 4 + quad][tt * 16 + l15][0];
#pragma unroll
            for (int jt = 0; jt < 6; ++jt)
#pragma unroll
                for (int tt = 0; tt < 4; ++tt)
                    acc[jt][tt] = MFMA16(afr[jt], bfr[tt], acc[jt][tt]);
        }

        // epilogue: 3 head-slices of 32 cols each. All of q/k/v use the same frag layout store.
#pragma unroll 1
        for (int s = 0; s < 3; ++s) {
            const int ob = cb + s * 32;
            const int which = ob / DIM;          // 0=q,1=k,2=v (wave-uniform)
            const int h = (ob % DIM) / 32;
            bf16* base = (which == 0) ? q_ws : (which == 1) ? k_ws : v_ws;
            float bias[2][4];
#pragma unroll
            for (int jl = 0; jl < 2; ++jl)
#pragma unroll
                for (int r = 0; r < 4; ++r)
                    bias[jl][r] = qkv_b[ob + jl * 16 + quad * 4 + r];

#pragma unroll
            for (int tt = 0; tt < 4; ++tt) {
                float v[2][4];
                float ss = 0.f;
#pragma unroll
                for (int jl = 0; jl < 2; ++jl)
#pragma unroll
                    for (int r = 0; r < 4; ++r) {
                        float t = acc[s * 2 + jl][tt][r] + bias[jl][r];
                        v[jl][r] = t;
                        ss += t * t;
                    }
                float inv = 1.f;
                if (which < 2) {
                    ss += __shfl_xor(ss, 16); ss += __shfl_xor(ss, 32);
                    inv = 1.f / fmaxf(sqrtf(ss), 1e-12f);
                }
                int token = t0 + tt * 16 + l15;   // D col
                int half = quad >> 1, e0 = (quad & 1) * 4;
#pragma unroll
                for (int jl = 0; jl < 2; ++jl) {
                    // frag layout [bh][jl][half][tok][8]: value = t[token][d=jl*16+half*8+e]
                    size_t addr = ((((size_t)(bl * NH + h) * 2 + jl) * 2 + half) * NT + token) * 8 + e0;
                    bf16x4 pk = {(bf16)(v[jl][0] * inv), (bf16)(v[jl][1] * inv),
                                 (bf16)(v[jl][2] * inv), (bf16)(v[jl][3] * inv)};
                    *(bf16x4*)(base + addr) = pk;
                }
            }
        }
    }
}

// ---------------- K2b: attention per (b,h). MFMA32 S^T / O^T, register P exchange ----------
__launch_bounds__(512, 4)
__global__ void k_attn(const bf16* __restrict__ q_ws, const bf16* __restrict__ k_ws,
                       const bf16* __restrict__ v_ws, bf16* __restrict__ xa, int b0) {
    __shared__ bf16 kfr[2][2][NT][8];   // 16,384 B: copy of k_ws slice [jl][half][tok][8]
    __shared__ bf16 vfr[32][32][8];     // 16,384 B: V transposed [oct][d][tok&7]
    const int h = blockIdx.x, bl = blockIdx.y;
    const int tid = threadIdx.x, lane = tid & 63, w = tid >> 6;
    const int l31 = lane & 31;
    const int half = lane >> 5;
    const bool hi_half = (half != 0);
    const f32x16 z16 = {0.f,0.f,0.f,0.f,0.f,0.f,0.f,0.f,0.f,0.f,0.f,0.f,0.f,0.f,0.f,0.f};

    // stage k (straight copy) and v (transpose). All reads of these happen after the barrier.
    {
        const bf16* ksrc = k_ws + (size_t)(bl * NH + h) * 8192;
        const bf16* vsrc = v_ws + (size_t)(bl * NH + h) * 8192;
        bf16* kdst = &kfr[0][0][0][0];
#pragma unroll
        for (int i = 0; i < 2; ++i) {
            int f = tid * 8 + i * 4096;
            *(bf16x8*)(kdst + f) = *(const bf16x8*)(ksrc + f);
            bf16x8 vv = *(const bf16x8*)(vsrc + f);
            int jl = f >> 12, hf = (f >> 11) & 1, tok = (f >> 3) & 255;
            int d0 = jl * 16 + hf * 8;
#pragma unroll
            for (int j = 0; j < 8; ++j)
                vfr[tok >> 3][d0 + j][tok & 7] = vv[j];
        }
    }
    // q B-frags direct from global (wave-private queries [w*32, w*32+32))
    const int q0 = w * 32;
    const bf16* qsrc = q_ws + (size_t)(bl * NH + h) * 8192;
    bf16x8 qf[2];
#pragma unroll
    for (int dk = 0; dk < 2; ++dk)
        qf[dk] = *(const bf16x8*)(qsrc + (((size_t)dk * 2 + half) * NT + q0 + l31) * 8);
    __syncthreads();

    f32x16 ot = z16;
    float dsum = 0.f;

#pragma unroll 1
    for (int kt = 0; kt < 8; ++kt) {
        // S^T tile: 32 keys x 32 queries, two d-halves
        bf16x8 ka0 = *(const bf16x8*)&kfr[0][half][kt * 32 + l31][0];
        bf16x8 ka1 = *(const bf16x8*)&kfr[1][half][kt * 32 + l31][0];
        f32x16 s = MFMA32(ka0, qf[0], z16);
        s = MFMA32(ka1, qf[1], s);
        // exp + pack. reg g2*4+r holds P^T[key = r+8*g2+4*half][query l31]
        U2H4 pk[4];
#pragma unroll
        for (int g2 = 0; g2 < 4; ++g2)
#pragma unroll
            for (int r = 0; r < 4; ++r) {
                float p = __expf(s[g2 * 4 + r] * SCALE);  // |logit|<=0.178: no max-sub
                dsum += p;
                pk[g2].h[r] = (bf16)p;
            }
        // P B-frag via xor-32 exchange: pf[j<4] = pk[c16*2+half]@half'0, pf[j>=4] = @half'1
#pragma unroll
        for (int c16 = 0; c16 < 2; ++c16) {
            uint2 A = hi_half ? pk[c16 * 2 + 1].u : pk[c16 * 2].u;      // own needed
            uint2 Bv = hi_half ? pk[c16 * 2].u     : pk[c16 * 2 + 1].u; // partner needed
            uint2 Bx = {(unsigned)__shfl_xor((int)Bv.x, 32), (unsigned)__shfl_xor((int)Bv.y, 32)};
            uint2 lo = hi_half ? Bx : A;
            uint2 hi = hi_half ? A : Bx;
            U4H8 pf; pf.u = (uint4){lo.x, lo.y, hi.x, hi.y};
            bf16x8 va = *(const bf16x8*)&vfr[kt * 4 + c16 * 2 + half][l31][0];
            ot = MFMA32(va, pf.h, ot);
        }
    }

    // denom: lane covers 16 keys/tile for query l31 -> xor-32 completes it
    dsum += __shfl_xor(dsum, 32);
    float inv = 1.f / dsum;

    // O^T regs -> xa via the same xor-32 exchange. od[g].h[r] = O[query l31][d=r+8g+4half]*inv
    U2H4 od[4];
#pragma unroll
    for (int g = 0; g < 4; ++g)
#pragma unroll
        for (int r = 0; r < 4; ++r)
            od[g].h[r] = (bf16)(ot[g * 4 + r] * inv);
    bf16* xap = xa + ((size_t)(bl * NT) + q0 + l31) * DIM + h * 32;
#pragma unroll
    for (int c = 0; c < 2; ++c) {
        // this lane stores channel group c8 = 2*half + c (d = c8*8 .. +7) of token q0+l31
        uint2 own = hi_half ? od[2 + c].u : od[c].u;      // od[c8]
        uint2 Bv  = hi_half ? od[c].u     : od[2 + c].u;  // partner's c8
        uint2 Bx = {(unsigned)__shfl_xor((int)Bv.x, 32), (unsigned)__shfl_xor((int)Bv.y, 32)};
        uint2 lo = hi_half ? Bx : own;
        uint2 hi = hi_half ? own : Bx;
        U4H8 ov; ov.u = (uint4){lo.x, lo.y, hi.x, hi.y};
        *(bf16x8*)(xap + (2 * half + c) * 8) = ov.h;
    }
}

// ---------------- K3: proj GEMM (32x32x16) + transposed f32 output ----------------
__launch_bounds__(256, 4)
__global__ void k_proj(const bf16* __restrict__ xa, const bf16* __restrict__ wp,
                       const float* __restrict__ proj_b, float* __restrict__ out, int b0) {
    const int cb = blockIdx.x, nb = blockIdx.y, bl = blockIdx.z;
    const int b = b0 + bl;
    const int tid = threadIdx.x, lane = tid & 63, w = tid >> 6;
    const int wc = w & 1, wn = w >> 1;
    const int l31 = lane & 31, half = lane >> 5;

    f32x16 acc[2][2];
#pragma unroll
    for (int i = 0; i < 2; ++i)
#pragma unroll
        for (int j = 0; j < 2; ++j)
#pragma unroll
            for (int r = 0; r < 16; ++r) acc[i][j][r] = 0.f;

    const bf16* ar[2];
    const bf16* br[2];
#pragma unroll
    for (int ct = 0; ct < 2; ++ct)
        ar[ct] = wp + (size_t)(cb * 128 + wc * 64 + ct * 32 + l31) * DIM + half * 8;
#pragma unroll
    for (int nt = 0; nt < 2; ++nt)
        br[nt] = xa + (size_t)(bl * NT + nb * 128 + wn * 64 + nt * 32 + l31) * DIM + half * 8;

#pragma unroll 2
    for (int kc = 0; kc < 24; ++kc) {
        int k0 = kc * 16;
        bf16x8 a0 = *(const bf16x8*)(ar[0] + k0);
        bf16x8 a1 = *(const bf16x8*)(ar[1] + k0);
        bf16x8 b0v = *(const bf16x8*)(br[0] + k0);
        bf16x8 b1v = *(const bf16x8*)(br[1] + k0);
        acc[0][0] = MFMA32(a0, b0v, acc[0][0]);
        acc[0][1] = MFMA32(a0, b1v, acc[0][1]);
        acc[1][0] = MFMA32(a1, b0v, acc[1][0]);
        acc[1][1] = MFMA32(a1, b1v, acc[1][1]);
    }

    float* op = out + (size_t)b * DIM * NT;
#pragma unroll
    for (int ct = 0; ct < 2; ++ct)
#pragma unroll
        for (int reg = 0; reg < 16; ++reg) {
            int row = (reg & 3) + 8 * (reg >> 2) + 4 * half;
            int c = cb * 128 + wc * 64 + ct * 32 + row;
            float bias = proj_b[c];
#pragma unroll
            for (int nt = 0; nt < 2; ++nt) {
                int n = nb * 128 + wn * 64 + nt * 32 + l31;  // 128B line
                op[(size_t)c * NT + n] = acc[ct][nt][reg] + bias;
            }
        }
}

extern "C" void kernel_launch(void* const* d_in, const int* in_sizes, int n_in,
                              void* d_out, int out_size, void* d_ws, size_t ws_size,
                              hipStream_t stream) {
    const float* x      = (const float*)d_in[0];
    const float* qkv_w  = (const float*)d_in[1];
    const float* qkv_b  = (const float*)d_in[2];
    const float* proj_w = (const float*)d_in[3];
    const float* proj_b = (const float*)d_in[4];
    float* out = (float*)d_out;

    // half-sized q/k/v/xa (128 b): 128*12*8192*2 B = 25,165,824 each
    char* ws = (char*)d_ws;
    bf16* q_ws = (bf16*)ws;                    // 25,165,824
    bf16* k_ws = (bf16*)(ws + 25165824);       // 25,165,824
    bf16* v_ws = (bf16*)(ws + 50331648);       // 25,165,824
    bf16* xa   = (bf16*)(ws + 75497472);       // 25,165,824
    bf16* wq   = (bf16*)(ws + 100663296);      // 884,736
    bf16* wp   = (bf16*)(ws + 101548032);      // 294,912  -> total 101,842,944

    k_cast_w<<<dim3(1728), dim3(256), 0, stream>>>(qkv_w, proj_w, wq, wp);
    for (int p = 0; p < 2; ++p) {
        int b0 = p * 128;
        k_qkv <<<dim3(4, 128),    dim3(256), 0, stream>>>(x, wq, qkv_b, q_ws, k_ws, v_ws, b0);
        k_attn<<<dim3(NH, 128),   dim3(512), 0, stream>>>(q_ws, k_ws, v_ws, xa, b0);
        k_proj<<<dim3(3, 2, 128), dim3(256), 0, stream>>>(xa, wp, proj_b, out, b0);
    }
}